// Round 13
// baseline (449.199 us; speedup 1.0000x reference)
//
#include <hip/hip_runtime.h>
#include <hip/hip_bf16.h>
#include <math.h>

#define NHEAD 8
#define CDIM 16
#define HCDIM 128
#define NGRAPH 64
#define WEXT 144   // 128 gemm cols + 8 src-coeff cols + 8 dst-coeff cols
#define SYPAD 136  // 128 + 8 shorts pad: row stride 68 dwords == 4 mod 32 banks

typedef __attribute__((ext_vector_type(8))) short short8;
typedef __attribute__((ext_vector_type(4))) float f32x4;

static __device__ __forceinline__ unsigned short f2bf(float f) {
    unsigned u = __float_as_uint(f);
    unsigned r = (u + 0x7FFF + ((u >> 16) & 1)) >> 16;   // rne
    return (unsigned short)r;
}
static __device__ __forceinline__ float bf2f(unsigned short s) {
    return __uint_as_float(((unsigned)s) << 16);
}

// ---------------------------------------------------------------- setup

// merged: zero deg/gsum + kcoef + graph_bounds + extended weight build
// + layer-1 coeff tables was1/wad1 [4][8]
__global__ void setup0(int* __restrict__ deg,
                       float* __restrict__ gsum,
                       const float* __restrict__ w2, const float* __restrict__ w3,
                       unsigned short* __restrict__ wt2h, unsigned short* __restrict__ wt2l,
                       unsigned short* __restrict__ wt3h, unsigned short* __restrict__ wt3l,
                       const float* __restrict__ we1, const float* __restrict__ ae1,
                       const float* __restrict__ we2, const float* __restrict__ ae2,
                       const float* __restrict__ we3, const float* __restrict__ ae3,
                       float* __restrict__ kc,
                       const float* __restrict__ as2, const float* __restrict__ ad2,
                       const float* __restrict__ as3, const float* __restrict__ ad3,
                       const float* __restrict__ w1,
                       const float* __restrict__ as1, const float* __restrict__ ad1,
                       float* __restrict__ wastab, float* __restrict__ wadtab,
                       const int* __restrict__ batch, int* __restrict__ gstart, int n) {
    int i = blockIdx.x * 256 + threadIdx.x;
    if (i < n) deg[i] = 0;
    if (i < NGRAPH * HCDIM) gsum[i] = 0.f;
    if (i < WEXT * HCDIM) {
        int nn = i >> 7, k = i & 127;
        float v2, v3;
        if (nn < HCDIM) {
            v2 = w2[k * HCDIM + nn];
            v3 = w3[k * HCDIM + nn];
        } else if (nn < HCDIM + NHEAD) {
            int h = nn - HCDIM;
            float s2 = 0.f, s3 = 0.f;
#pragma unroll
            for (int c = 0; c < CDIM; ++c) {
                s2 += w2[k * HCDIM + h * CDIM + c] * as2[h * CDIM + c];
                s3 += w3[k * HCDIM + h * CDIM + c] * as3[h * CDIM + c];
            }
            v2 = s2; v3 = s3;
        } else {
            int h = nn - HCDIM - NHEAD;
            float s2 = 0.f, s3 = 0.f;
#pragma unroll
            for (int c = 0; c < CDIM; ++c) {
                s2 += w2[k * HCDIM + h * CDIM + c] * ad2[h * CDIM + c];
                s3 += w3[k * HCDIM + h * CDIM + c] * ad3[h * CDIM + c];
            }
            v2 = s2; v3 = s3;
        }
        unsigned short h2 = f2bf(v2);
        wt2h[nn * HCDIM + k] = h2;
        wt2l[nn * HCDIM + k] = f2bf(v2 - bf2f(h2));
        unsigned short h3 = f2bf(v3);
        wt3h[nn * HCDIM + k] = h3;
        wt3l[nn * HCDIM + k] = f2bf(v3 - bf2f(h3));
    }
    if (i < 24) {
        int l = i >> 3, h = i & 7;
        const float* we = (l == 0) ? we1 : ((l == 1) ? we2 : we3);
        const float* ae = (l == 0) ? ae1 : ((l == 1) ? ae2 : ae3);
        float s = 0.f;
        for (int c = 0; c < CDIM; ++c) s += we[h * CDIM + c] * ae[h * CDIM + c];
        kc[i] = s;
    }
    if (i >= 18560 && i <= 18560 + NGRAPH) {   // graph bounds, disjoint range
        int g = i - 18560;
        int lo = 0, hi = n;
        while (lo < hi) {
            int mid = (lo + hi) >> 1;
            if (batch[mid] < g) lo = mid + 1; else hi = mid;
        }
        gstart[g] = lo;
    }
    if (i >= 18700 && i < 18732) {   // layer-1 coeff tables [4][8]
        int t = i - 18700;
        int k = t >> 3, h = t & 7;
        float ss = 0.f, sd = 0.f;
#pragma unroll
        for (int c = 0; c < CDIM; ++c) {
            ss += w1[k * HCDIM + h * CDIM + c] * as1[h * CDIM + c];
            sd += w1[k * HCDIM + h * CDIM + c] * ad1[h * CDIM + c];
        }
        wastab[t] = ss;
        wadtab[t] = sd;
    }
}

// counts degree AND records each edge's within-dst rank so scatter is atomic-free.
__global__ void count_deg(const int* __restrict__ dst, int* __restrict__ deg,
                          int* __restrict__ erank, int E) {
    int e = blockIdx.x * 256 + threadIdx.x;
    if (e >= E) return;
    erank[e] = atomicAdd(&deg[dst[e]], 1);
}

__global__ __launch_bounds__(512) void block_sum(const int* __restrict__ deg,
                                                 int* __restrict__ bsum, int n) {
    __shared__ int s[512];
    int i = blockIdx.x * 512 + threadIdx.x;
    s[threadIdx.x] = (i < n) ? deg[i] : 0;
    __syncthreads();
    for (int off = 256; off > 0; off >>= 1) {
        if (threadIdx.x < off) s[threadIdx.x] += s[threadIdx.x + off];
        __syncthreads();
    }
    if (threadIdx.x == 0) bsum[blockIdx.x] = s[0];
}

// fused: every block scans the (<=512-entry) bsum array in LDS AND its own
// 512-entry deg slice, producing eoff directly.
__global__ __launch_bounds__(512) void scan_final2(const int* __restrict__ deg,
                                                   const int* __restrict__ bsum, int nb,
                                                   int* __restrict__ eoff, int n) {
    __shared__ int ls[512];
    __shared__ int s[512];
    const int t = threadIdx.x;
    ls[t] = (t < nb) ? bsum[t] : 0;
    int i = blockIdx.x * 512 + t;
    s[t] = (i < n) ? deg[i] : 0;
    __syncthreads();
    for (int off = 1; off < 512; off <<= 1) {
        int a1 = (t >= off) ? ls[t - off] : 0;
        int a2 = (t >= off) ? s[t - off] : 0;
        __syncthreads();
        ls[t] += a1; s[t] += a2;
        __syncthreads();
    }
    int base = (blockIdx.x > 0) ? ls[blockIdx.x - 1] : 0;   // exclusive block base
    if (i < n) eoff[i + 1] = base + s[t];
    if (i == 0) eoff[0] = 0;
}

// atomic-free scatter: position = eoff[dst] + precomputed rank.
__global__ void scatter_edges(const int* __restrict__ src, const int* __restrict__ dst,
                              const float* __restrict__ eattr,
                              const int* __restrict__ eoff,
                              const int* __restrict__ erank,
                              int2* __restrict__ epack, int E) {
    int e = blockIdx.x * 256 + threadIdx.x;
    if (e >= E) return;
    int p = eoff[dst[e]] + erank[e];
    epack[p] = make_int2(src[e], __float_as_int(eattr[e]));
}

// ---------------------------------------------------------------- layer-1 aggregate

// h is rank-4, and by linearity  Σ_e w_e·(x_e@W1) = (Σ_e w_e·x_e)@W1.
// Edge loop accumulates the per-head weighted 4-vector + den (5 MAC/edge);
// the W1 expansion (16 FMA) runs ONCE per node in the epilogue.
__global__ __launch_bounds__(256) void gat_aggregate1(
    const float* __restrict__ x,        // [n,4]
    const int2*  __restrict__ epack,    // [E] dst-sorted {src, bits(eattr)}
    const int*   __restrict__ eoff,     // [n+1]
    const float* __restrict__ w1,       // [4][128]
    const float* __restrict__ wastab,   // [4][8]
    const float* __restrict__ wadtab,   // [4][8]
    const float* __restrict__ kc,       // [8]
    const float* __restrict__ bias,     // [128]
    unsigned short* __restrict__ outhi, // [n,128]
    unsigned short* __restrict__ outlo, int n) {
    const int lane = threadIdx.x & 63;
    const int hl = lane & 31;
    int nid = ((blockIdx.x * 256 + threadIdx.x) >> 6) * 2 + (lane >> 5);
    if (nid >= n) return;
    const int h = hl >> 2;            // 4 lanes per head
    const int c0 = hl * 4;            // 4 contiguous channels per lane

    float was0 = wastab[0 * NHEAD + h], was1_ = wastab[1 * NHEAD + h];
    float was2 = wastab[2 * NHEAD + h], was3 = wastab[3 * NHEAD + h];
    float wad0 = wadtab[0 * NHEAD + h], wad1_ = wadtab[1 * NHEAD + h];
    float wad2 = wadtab[2 * NHEAD + h], wad3 = wadtab[3 * NHEAD + h];

    float4 xd = *(const float4*)(x + (long)nid * 4);
    const float adst_h = xd.x * wad0 + xd.y * wad1_ + xd.z * wad2 + xd.w * wad3;
    const float k_h = kc[h];
    const int e0 = eoff[nid], e1 = eoff[nid + 1];

    float den = 0.f;
    float a0 = 0.f, a1 = 0.f, a2 = 0.f, a3 = 0.f;   // Σ w_e · x_e (per head)

    for (int base = e0; base < e1; base += 4) {
        int2 ep[4];
#pragma unroll
        for (int j = 0; j < 4; ++j) {
            int idx = base + j; idx = (idx < e1) ? idx : (e1 - 1);
            ep[j] = epack[idx];
        }
        float4 xs[4];
#pragma unroll
        for (int j = 0; j < 4; ++j) xs[j] = *(const float4*)(x + (long)ep[j].x * 4);
#pragma unroll
        for (int j = 0; j < 4; ++j) {
            bool valid = (base + j < e1);
            float as_e = xs[j].x * was0 + xs[j].y * was1_ + xs[j].z * was2 + xs[j].w * was3;
            float a = as_e + adst_h + __int_as_float(ep[j].y) * k_h;
            a = (a > 0.f) ? a : 0.2f * a;
            float w = valid ? __expf(a) : 0.f;
            den += w;
            a0 += xs[j].x * w; a1 += xs[j].y * w;
            a2 += xs[j].z * w; a3 += xs[j].w * w;
        }
    }

    // epilogue: expand acc4 through W1 columns (once per node)
    float inv = 1.f / (den + 1e-16f);
    float4 wk0 = *(const float4*)(w1 + 0 * HCDIM + c0);
    float4 wk1 = *(const float4*)(w1 + 1 * HCDIM + c0);
    float4 wk2 = *(const float4*)(w1 + 2 * HCDIM + c0);
    float4 wk3 = *(const float4*)(w1 + 3 * HCDIM + c0);
    float4 bv = *(const float4*)(bias + c0);
    float o0 = fmaxf((a0 * wk0.x + a1 * wk1.x + a2 * wk2.x + a3 * wk3.x) * inv + bv.x, 0.f);
    float o1 = fmaxf((a0 * wk0.y + a1 * wk1.y + a2 * wk2.y + a3 * wk3.y) * inv + bv.y, 0.f);
    float o2 = fmaxf((a0 * wk0.z + a1 * wk1.z + a2 * wk2.z + a3 * wk3.z) * inv + bv.z, 0.f);
    float o3 = fmaxf((a0 * wk0.w + a1 * wk1.w + a2 * wk2.w + a3 * wk3.w) * inv + bv.w, 0.f);
    unsigned short h0 = f2bf(o0), h1 = f2bf(o1), h2 = f2bf(o2), h3 = f2bf(o3);
    ushort4 hi = make_ushort4(h0, h1, h2, h3);
    ushort4 lo = make_ushort4(f2bf(o0 - bf2f(h0)), f2bf(o1 - bf2f(h1)),
                              f2bf(o2 - bf2f(h2)), f2bf(o3 - bf2f(h3)));
    *(ushort4*)(outhi + (long)nid * HCDIM + c0) = hi;
    *(ushort4*)(outlo + (long)nid * HCDIM + c0) = lo;
}

// ---------------------------------------------------------------- gemm

// layers 2/3: [n,128] @ [128,144] via split-bf16 MFMA.
// v3: ONE 16-row group per wave (36 acc regs, 2x waves vs v2) and
// LDS-transposed epilogue -> 4 dwordx4 stores/lane instead of 64 2-byte
// stores/lane. cols 0..127 -> Ybf (bf16); col-tile 8 -> attn coeffs (fp32).
__global__ __launch_bounds__(256) void gemm_mfma(const unsigned short* __restrict__ Ahi,
                                                 const unsigned short* __restrict__ Alo,
                                                 const unsigned short* __restrict__ Wth,
                                                 const unsigned short* __restrict__ Wtl,
                                                 unsigned short* __restrict__ Ybf,
                                                 float* __restrict__ asrcn,
                                                 float* __restrict__ adstn, int n) {
    __shared__ unsigned short sY[4][16][SYPAD];
    const int wave = threadIdx.x >> 6;
    const int lane = threadIdx.x & 63;
    const int quad = lane >> 4;
    const int l16  = lane & 15;
    const int rowbase = (blockIdx.x * 4 + wave) * 16;

    f32x4 acc[9];
#pragma unroll
    for (int t = 0; t < 9; ++t) acc[t] = (f32x4){0.f, 0.f, 0.f, 0.f};

#pragma unroll
    for (int kb = 0; kb < HCDIM; kb += 32) {
        int row = rowbase + l16;
        row = (row < n) ? row : (n - 1);
        const long aoff = (long)row * HCDIM + kb + quad * 8;
        short8 ah = *(const short8*)(Ahi + aoff);
        short8 al = *(const short8*)(Alo + aoff);
#pragma unroll
        for (int nt = 0; nt < 9; ++nt) {
            const long woff = (long)(nt * 16 + l16) * HCDIM + kb + quad * 8;
            short8 bh = *(const short8*)(Wth + woff);
            short8 bl = *(const short8*)(Wtl + woff);
            acc[nt] = __builtin_amdgcn_mfma_f32_16x16x32_bf16(ah, bh, acc[nt], 0, 0, 0);
            acc[nt] = __builtin_amdgcn_mfma_f32_16x16x32_bf16(al, bh, acc[nt], 0, 0, 0);
            acc[nt] = __builtin_amdgcn_mfma_f32_16x16x32_bf16(ah, bl, acc[nt], 0, 0, 0);
        }
    }

    // C/D layout: col = l16, row_local = quad*4 + reg.
    // cols 0..127 -> per-wave LDS tile (no barrier: wave-private)
#pragma unroll
    for (int nt = 0; nt < 8; ++nt)
#pragma unroll
        for (int reg = 0; reg < 4; ++reg)
            sY[wave][quad * 4 + reg][nt * 16 + l16] = f2bf(acc[nt][reg]);
    // coeff tile (nt=8): scalar stores, 8 per lane-group
#pragma unroll
    for (int reg = 0; reg < 4; ++reg) {
        int row = rowbase + quad * 4 + reg;
        if (row < n) {
            float cv = acc[8][reg];
            if (l16 < 8) asrcn[row * NHEAD + l16] = cv;
            else         adstn[row * NHEAD + (l16 - 8)] = cv;
        }
    }
    __builtin_amdgcn_s_waitcnt(0);   // lgkmcnt(0): LDS writes visible to own wave
    // coalesced stores: 256 16-byte units (16 rows x 16 units), 4 rounds
#pragma unroll
    for (int j = 0; j < 4; ++j) {
        int idx = j * 64 + lane;
        int row = idx >> 4;
        int colu = idx & 15;
        int gr = rowbase + row;
        if (gr < n)
            *(ushort4*)(Ybf + (long)gr * HCDIM + colu * 8) =
                *(ushort4*)(&sY[wave][row][colu * 8]);
        idx += 0;  // (two ushort4 = 16B via pair)
        if (gr < n)
            *(ushort4*)(Ybf + (long)gr * HCDIM + colu * 8 + 4) =
                *(ushort4*)(&sY[wave][row][colu * 8 + 4]);
    }
}

// ---------------------------------------------------------------- aggregate (layers 2/3)

// TWO nodes per wave (32 lanes x 4 channels each); single pass, no
// max-subtraction. 4-way unrolled edge loop. h gathered as BF16 (8 B/lane);
// accumulation stays fp32.
__global__ __launch_bounds__(256) void gat_aggregate(
    const unsigned short* __restrict__ hlin, // [n,128] bf16
    const float* __restrict__ asrc,     // [n,8]
    const float* __restrict__ adst,     // [n,8]
    const int2*  __restrict__ epack,    // [E] dst-sorted {src, bits(eattr)}
    const int*   __restrict__ eoff,     // [n+1]
    const float* __restrict__ kc,       // [8] this layer
    const float* __restrict__ bias,     // [128]
    float* __restrict__ outf,           // [n,128] (split_out=0)
    unsigned short* __restrict__ outhi, // [n,128] (split_out=1)
    unsigned short* __restrict__ outlo,
    int n, int use_loop, int split_out) {
    const int lane = threadIdx.x & 63;
    const int hl = lane & 31;
    int nid = ((blockIdx.x * 256 + threadIdx.x) >> 6) * 2 + (lane >> 5);
    if (nid >= n) return;
    const int h = hl >> 2;            // 4 lanes per head
    const int c0 = hl * 4;            // 4 contiguous channels per lane

    const float adst_h = adst[nid * NHEAD + h];
    const float k_h = kc[h];
    const int e0 = eoff[nid], e1 = eoff[nid + 1];

    float den = 0.f, sume = 0.f;
    float ax = 0.f, ay = 0.f, az = 0.f, aw = 0.f;

    for (int base = e0; base < e1; base += 4) {
        int2 ep[4];
#pragma unroll
        for (int j = 0; j < 4; ++j) {
            int idx = base + j; idx = (idx < e1) ? idx : (e1 - 1);
            ep[j] = epack[idx];
        }
        float av[4]; ushort4 hv[4];
#pragma unroll
        for (int j = 0; j < 4; ++j) {
            av[j] = asrc[ep[j].x * NHEAD + h];
            hv[j] = *(const ushort4*)(hlin + (long)ep[j].x * HCDIM + c0);
        }
#pragma unroll
        for (int j = 0; j < 4; ++j) {
            bool valid = (base + j < e1);
            float ea = __int_as_float(ep[j].y);
            float a = av[j] + adst_h + ea * k_h;
            a = (a > 0.f) ? a : 0.2f * a;
            float w = valid ? __expf(a) : 0.f;
            sume += valid ? ea : 0.f;
            den += w;
            ax += bf2f(hv[j].x) * w; ay += bf2f(hv[j].y) * w;
            az += bf2f(hv[j].z) * w; aw += bf2f(hv[j].w) * w;
        }
    }

    if (use_loop) {   // self-loop; attr = mean of incoming eattr
        float fl = sume / fmaxf((float)(e1 - e0), 1.f);
        float a = asrc[nid * NHEAD + h] + adst_h + fl * k_h;
        a = (a > 0.f) ? a : 0.2f * a;
        float w = __expf(a);
        ushort4 hv = *(const ushort4*)(hlin + (long)nid * HCDIM + c0);
        den += w;
        ax += bf2f(hv.x) * w; ay += bf2f(hv.y) * w;
        az += bf2f(hv.z) * w; aw += bf2f(hv.w) * w;
    }

    float inv = 1.f / (den + 1e-16f);
    float4 bv = *(const float4*)(bias + c0);
    float o0 = fmaxf(ax * inv + bv.x, 0.f);
    float o1 = fmaxf(ay * inv + bv.y, 0.f);
    float o2 = fmaxf(az * inv + bv.z, 0.f);
    float o3 = fmaxf(aw * inv + bv.w, 0.f);
    if (split_out) {
        unsigned short h0 = f2bf(o0), h1 = f2bf(o1), h2 = f2bf(o2), h3 = f2bf(o3);
        ushort4 hi = make_ushort4(h0, h1, h2, h3);
        ushort4 lo = make_ushort4(f2bf(o0 - bf2f(h0)), f2bf(o1 - bf2f(h1)),
                                  f2bf(o2 - bf2f(h2)), f2bf(o3 - bf2f(h3)));
        *(ushort4*)(outhi + (long)nid * HCDIM + c0) = hi;
        *(ushort4*)(outlo + (long)nid * HCDIM + c0) = lo;
    } else {
        *(float4*)(outf + (long)nid * HCDIM + c0) = make_float4(o0, o1, o2, o3);
    }
}

// ---------------------------------------------------------------- pool + MLP

// segmented pool: block = (graph g, chunk) over the CONTIGUOUS row range
// gstart[g]..gstart[g+1] (batch is sorted). One atomic per column per chunk.
__global__ __launch_bounds__(128) void pool_seg(const float* __restrict__ H,
                                                const int* __restrict__ gstart,
                                                float* __restrict__ gsum) {
    const int c = threadIdx.x;            // 0..127
    const int g = blockIdx.x >> 3;
    const int chunk = blockIdx.x & 7;
    int s0 = gstart[g], s1 = gstart[g + 1];
    int len = s1 - s0;
    if (len <= 0) return;
    int cl = (len + 7) >> 3;
    int i0 = s0 + chunk * cl;
    int i1 = min(i0 + cl, s1);
    if (i0 >= i1) return;
    float acc = 0.f;
    int i = i0;
    for (; i + 4 <= i1; i += 4) {
        float v0 = H[(long)i * HCDIM + c];
        float v1 = H[(long)(i + 1) * HCDIM + c];
        float v2 = H[(long)(i + 2) * HCDIM + c];
        float v3 = H[(long)(i + 3) * HCDIM + c];
        acc += (v0 + v1) + (v2 + v3);
    }
    for (; i < i1; ++i) acc += H[(long)i * HCDIM + c];
    atomicAdd(&gsum[g * HCDIM + c], acc);
}

__global__ __launch_bounds__(64) void mlp_kernel(const float* __restrict__ gsum,
                                                 const int* __restrict__ gstart,
                                                 const float* __restrict__ fw1,
                                                 const float* __restrict__ fb1,
                                                 const float* __restrict__ fw2,
                                                 const float* __restrict__ fb2,
                                                 float* __restrict__ out) {
    const int g = blockIdx.x;
    const int j = threadIdx.x;            // 0..63
    __shared__ float emb[HCDIM];
    __shared__ float gh[64];
    int cnt = gstart[g + 1] - gstart[g];
    float invc = 1.f / fmaxf((float)cnt, 1.f);
    emb[j] = gsum[g * HCDIM + j] * invc;
    emb[j + 64] = gsum[g * HCDIM + 64 + j] * invc;
    __syncthreads();
    float a = fb1[j];
    for (int k = 0; k < HCDIM; ++k) a += emb[k] * fw1[k * 64 + j];
    gh[j] = fmaxf(a, 0.f);
    __syncthreads();
    if (j < 2) {
        float o = fb2[j];
        for (int k = 0; k < 64; ++k) o += gh[k] * fw2[k * 2 + j];
        out[g * 2 + j] = o;
    }
}

// ---------------------------------------------------------------- launcher

extern "C" void kernel_launch(void* const* d_in, const int* in_sizes, int n_in,
                              void* d_out, int out_size, void* d_ws, size_t ws_size,
                              hipStream_t stream) {
    const float* x     = (const float*)d_in[0];
    const int*   eidx  = (const int*)d_in[1];
    const float* eattr = (const float*)d_in[2];
    const int*   batch = (const int*)d_in[3];
    const float* w1  = (const float*)d_in[4];
    const float* as1 = (const float*)d_in[5];
    const float* ad1 = (const float*)d_in[6];
    const float* we1 = (const float*)d_in[7];
    const float* ae1 = (const float*)d_in[8];
    const float* b1  = (const float*)d_in[9];
    const float* w2  = (const float*)d_in[10];
    const float* as2 = (const float*)d_in[11];
    const float* ad2 = (const float*)d_in[12];
    const float* we2 = (const float*)d_in[13];
    const float* ae2 = (const float*)d_in[14];
    const float* b2  = (const float*)d_in[15];
    const float* w3  = (const float*)d_in[16];
    const float* as3 = (const float*)d_in[17];
    const float* ad3 = (const float*)d_in[18];
    const float* we3 = (const float*)d_in[19];
    const float* ae3 = (const float*)d_in[20];
    const float* b3  = (const float*)d_in[21];
    const float* fw1 = (const float*)d_in[22];
    const float* fb1 = (const float*)d_in[23];
    const float* fw2 = (const float*)d_in[24];
    const float* fb2 = (const float*)d_in[25];

    const int N = in_sizes[3];
    const int E = in_sizes[2];
    const int* src = eidx;
    const int* dst = eidx + E;

    // workspace carve
    char* p = (char*)d_ws;
    auto alloc = [&](size_t bytes) {
        void* r = (void*)p;
        p += (bytes + 255) & ~(size_t)255;
        return r;
    };
    // A: gemm output in bf16 [n,128]
    unsigned short* Abf = (unsigned short*)alloc((size_t)N * HCDIM * 2);
    // B region: bf16 hi/lo pair (layers 1-2) ALIASED with fp32 (layer 3 -> pool).
    char*  Bbuf   = (char*)alloc((size_t)N * HCDIM * 4);
    unsigned short* Bhi = (unsigned short*)Bbuf;
    unsigned short* Blo = Bhi + (size_t)N * HCDIM;
    float* Bf32   = (float*)Bbuf;
    float* asrcA  = (float*)alloc((size_t)N * NHEAD * 4);
    float* adstA  = (float*)alloc((size_t)N * NHEAD * 4);
    float* asrcB  = (float*)alloc((size_t)N * NHEAD * 4);
    float* adstB  = (float*)alloc((size_t)N * NHEAD * 4);
    int*   deg    = (int*)alloc((size_t)N * 4);
    int*   eoff   = (int*)alloc((size_t)(N + 1) * 4);
    int*   erank  = (int*)alloc((size_t)E * 4);
    int2*  epack  = (int2*)alloc((size_t)E * 8);
    int*   bsum   = (int*)alloc(((size_t)(N + 511) / 512) * 4);
    float* kc     = (float*)alloc(24 * 4);
    int*   gstart = (int*)alloc((NGRAPH + 1) * 4);
    float* gsum   = (float*)alloc(NGRAPH * HCDIM * 4);
    float* wastab = (float*)alloc(32 * 4);
    float* wadtab = (float*)alloc(32 * 4);
    unsigned short* wt2h = (unsigned short*)alloc(WEXT * HCDIM * 2);
    unsigned short* wt2l = (unsigned short*)alloc(WEXT * HCDIM * 2);
    unsigned short* wt3h = (unsigned short*)alloc(WEXT * HCDIM * 2);
    unsigned short* wt3l = (unsigned short*)alloc(WEXT * HCDIM * 2);

    const int NB = (N + 255) / 256;
    const int NB512 = (N + 511) / 512;
    const int EB = (E + 255) / 256;
    const int AGG_BLOCKS = (((N + 1) / 2) * 64 + 255) / 256;   // 2 nodes/wave
    const int GEMM_BLOCKS = (N + 63) / 64;                     // 64 rows per block

    setup0<<<NB, 256, 0, stream>>>(deg, gsum,
                                   w2, w3, wt2h, wt2l, wt3h, wt3l,
                                   we1, ae1, we2, ae2, we3, ae3, kc,
                                   as2, ad2, as3, ad3,
                                   w1, as1, ad1, wastab, wadtab,
                                   batch, gstart, N);
    count_deg<<<EB, 256, 0, stream>>>(dst, deg, erank, E);
    block_sum<<<NB512, 512, 0, stream>>>(deg, bsum, N);
    scan_final2<<<NB512, 512, 0, stream>>>(deg, bsum, NB512, eoff, N);
    scatter_edges<<<EB, 256, 0, stream>>>(src, dst, eattr, eoff, erank, epack, E);

    // layer 1 (no self loops): rank-4 accumulate + epilogue W1 expand
    gat_aggregate1<<<AGG_BLOCKS, 256, 0, stream>>>(x, epack, eoff, w1, wastab, wadtab,
                                                   kc + 0, b1, Bhi, Blo, N);
    // layer 2: gemm emits bf16 h2 + layer-2 coeffs (fp32, from extended W2)
    gemm_mfma<<<GEMM_BLOCKS, 256, 0, stream>>>(Bhi, Blo, wt2h, wt2l, Abf, asrcB, adstB, N);
    gat_aggregate<<<AGG_BLOCKS, 256, 0, stream>>>(Abf, asrcB, adstB, epack, eoff,
                                                  kc + 8, b2, Bf32, Bhi, Blo, N, 1, 1);
    // layer 3: gemm emits bf16 h3 + layer-3 coeffs; agg out fp32 -> pool
    gemm_mfma<<<GEMM_BLOCKS, 256, 0, stream>>>(Bhi, Blo, wt3h, wt3l, Abf, asrcA, adstA, N);
    gat_aggregate<<<AGG_BLOCKS, 256, 0, stream>>>(Abf, asrcA, adstA, epack, eoff,
                                                  kc + 16, b3, Bf32, Bhi, Blo, N, 1, 0);

    // segmented mean-pool + MLP head
    pool_seg<<<NGRAPH * 8, 128, 0, stream>>>(Bf32, gstart, gsum);
    mlp_kernel<<<NGRAPH, 64, 0, stream>>>(gsum, gstart, fw1, fb1, fw2, fb2, (float*)d_out);
}

// Round 14
// 347.711 us; speedup vs baseline: 1.2919x; 1.2919x over previous
//
#include <hip/hip_runtime.h>
#include <hip/hip_bf16.h>
#include <math.h>

#define NHEAD 8
#define CDIM 16
#define HCDIM 128
#define NGRAPH 64
#define WEXT 144   // 128 gemm cols + 8 src-coeff cols + 8 dst-coeff cols
#define SWPAD 136  // +8 shorts pad: row stride 68 dwords == 4 mod 32 banks

typedef __attribute__((ext_vector_type(8))) short short8;
typedef __attribute__((ext_vector_type(4))) float f32x4;

static __device__ __forceinline__ unsigned short f2bf(float f) {
    unsigned u = __float_as_uint(f);
    unsigned r = (u + 0x7FFF + ((u >> 16) & 1)) >> 16;   // rne
    return (unsigned short)r;
}
static __device__ __forceinline__ float bf2f(unsigned short s) {
    return __uint_as_float(((unsigned)s) << 16);
}

// ---------------------------------------------------------------- setup

// merged: zero deg/gsum + kcoef + graph_bounds + extended weight build
// (single bf16 — no lo split; error budget: h is already bf16-rounded at the
// same 2^-9 magnitude and measured absmax was 7.6e-6 vs 2.9e-4 threshold)
// + layer-1 coeff tables was1/wad1 [4][8]
__global__ void setup0(int* __restrict__ deg,
                       float* __restrict__ gsum,
                       const float* __restrict__ w2, const float* __restrict__ w3,
                       unsigned short* __restrict__ wt2, unsigned short* __restrict__ wt3,
                       const float* __restrict__ we1, const float* __restrict__ ae1,
                       const float* __restrict__ we2, const float* __restrict__ ae2,
                       const float* __restrict__ we3, const float* __restrict__ ae3,
                       float* __restrict__ kc,
                       const float* __restrict__ as2, const float* __restrict__ ad2,
                       const float* __restrict__ as3, const float* __restrict__ ad3,
                       const float* __restrict__ w1,
                       const float* __restrict__ as1, const float* __restrict__ ad1,
                       float* __restrict__ wastab, float* __restrict__ wadtab,
                       const int* __restrict__ batch, int* __restrict__ gstart, int n) {
    int i = blockIdx.x * 256 + threadIdx.x;
    if (i < n) deg[i] = 0;
    if (i < NGRAPH * HCDIM) gsum[i] = 0.f;
    if (i < WEXT * HCDIM) {
        int nn = i >> 7, k = i & 127;
        float v2, v3;
        if (nn < HCDIM) {
            v2 = w2[k * HCDIM + nn];
            v3 = w3[k * HCDIM + nn];
        } else if (nn < HCDIM + NHEAD) {
            int h = nn - HCDIM;
            float s2 = 0.f, s3 = 0.f;
#pragma unroll
            for (int c = 0; c < CDIM; ++c) {
                s2 += w2[k * HCDIM + h * CDIM + c] * as2[h * CDIM + c];
                s3 += w3[k * HCDIM + h * CDIM + c] * as3[h * CDIM + c];
            }
            v2 = s2; v3 = s3;
        } else {
            int h = nn - HCDIM - NHEAD;
            float s2 = 0.f, s3 = 0.f;
#pragma unroll
            for (int c = 0; c < CDIM; ++c) {
                s2 += w2[k * HCDIM + h * CDIM + c] * ad2[h * CDIM + c];
                s3 += w3[k * HCDIM + h * CDIM + c] * ad3[h * CDIM + c];
            }
            v2 = s2; v3 = s3;
        }
        wt2[nn * HCDIM + k] = f2bf(v2);
        wt3[nn * HCDIM + k] = f2bf(v3);
    }
    if (i < 24) {
        int l = i >> 3, h = i & 7;
        const float* we = (l == 0) ? we1 : ((l == 1) ? we2 : we3);
        const float* ae = (l == 0) ? ae1 : ((l == 1) ? ae2 : ae3);
        float s = 0.f;
        for (int c = 0; c < CDIM; ++c) s += we[h * CDIM + c] * ae[h * CDIM + c];
        kc[i] = s;
    }
    if (i >= 18560 && i <= 18560 + NGRAPH) {   // graph bounds, disjoint range
        int g = i - 18560;
        int lo = 0, hi = n;
        while (lo < hi) {
            int mid = (lo + hi) >> 1;
            if (batch[mid] < g) lo = mid + 1; else hi = mid;
        }
        gstart[g] = lo;
    }
    if (i >= 18700 && i < 18732) {   // layer-1 coeff tables [4][8]
        int t = i - 18700;
        int k = t >> 3, h = t & 7;
        float ss = 0.f, sd = 0.f;
#pragma unroll
        for (int c = 0; c < CDIM; ++c) {
            ss += w1[k * HCDIM + h * CDIM + c] * as1[h * CDIM + c];
            sd += w1[k * HCDIM + h * CDIM + c] * ad1[h * CDIM + c];
        }
        wastab[t] = ss;
        wadtab[t] = sd;
    }
}

// counts degree AND records each edge's within-dst rank so scatter is atomic-free.
__global__ void count_deg(const int* __restrict__ dst, int* __restrict__ deg,
                          int* __restrict__ erank, int E) {
    int e = blockIdx.x * 256 + threadIdx.x;
    if (e >= E) return;
    erank[e] = atomicAdd(&deg[dst[e]], 1);
}

__global__ __launch_bounds__(512) void block_sum(const int* __restrict__ deg,
                                                 int* __restrict__ bsum, int n) {
    __shared__ int s[512];
    int i = blockIdx.x * 512 + threadIdx.x;
    s[threadIdx.x] = (i < n) ? deg[i] : 0;
    __syncthreads();
    for (int off = 256; off > 0; off >>= 1) {
        if (threadIdx.x < off) s[threadIdx.x] += s[threadIdx.x + off];
        __syncthreads();
    }
    if (threadIdx.x == 0) bsum[blockIdx.x] = s[0];
}

// fused: every block scans the (<=512-entry) bsum array in LDS AND its own
// 512-entry deg slice, producing eoff directly.
__global__ __launch_bounds__(512) void scan_final2(const int* __restrict__ deg,
                                                   const int* __restrict__ bsum, int nb,
                                                   int* __restrict__ eoff, int n) {
    __shared__ int ls[512];
    __shared__ int s[512];
    const int t = threadIdx.x;
    ls[t] = (t < nb) ? bsum[t] : 0;
    int i = blockIdx.x * 512 + t;
    s[t] = (i < n) ? deg[i] : 0;
    __syncthreads();
    for (int off = 1; off < 512; off <<= 1) {
        int a1 = (t >= off) ? ls[t - off] : 0;
        int a2 = (t >= off) ? s[t - off] : 0;
        __syncthreads();
        ls[t] += a1; s[t] += a2;
        __syncthreads();
    }
    int base = (blockIdx.x > 0) ? ls[blockIdx.x - 1] : 0;   // exclusive block base
    if (i < n) eoff[i + 1] = base + s[t];
    if (i == 0) eoff[0] = 0;
}

// atomic-free scatter: position = eoff[dst] + precomputed rank.
__global__ void scatter_edges(const int* __restrict__ src, const int* __restrict__ dst,
                              const float* __restrict__ eattr,
                              const int* __restrict__ eoff,
                              const int* __restrict__ erank,
                              int2* __restrict__ epack, int E) {
    int e = blockIdx.x * 256 + threadIdx.x;
    if (e >= E) return;
    int p = eoff[dst[e]] + erank[e];
    epack[p] = make_int2(src[e], __float_as_int(eattr[e]));
}

// ---------------------------------------------------------------- layer-1 aggregate

// h is rank-4:  Σ_e w_e·(x_e@W1) = (Σ_e w_e·x_e)@W1.
// Edge loop: 5 MAC/edge; W1 expansion once per node in the epilogue.
__global__ __launch_bounds__(256) void gat_aggregate1(
    const float* __restrict__ x,        // [n,4]
    const int2*  __restrict__ epack,    // [E] dst-sorted {src, bits(eattr)}
    const int*   __restrict__ eoff,     // [n+1]
    const float* __restrict__ w1,       // [4][128]
    const float* __restrict__ wastab,   // [4][8]
    const float* __restrict__ wadtab,   // [4][8]
    const float* __restrict__ kc,       // [8]
    const float* __restrict__ bias,     // [128]
    unsigned short* __restrict__ outbf, // [n,128] bf16
    int n) {
    const int lane = threadIdx.x & 63;
    const int hl = lane & 31;
    int nid = ((blockIdx.x * 256 + threadIdx.x) >> 6) * 2 + (lane >> 5);
    if (nid >= n) return;
    const int h = hl >> 2;            // 4 lanes per head
    const int c0 = hl * 4;            // 4 contiguous channels per lane

    float was0 = wastab[0 * NHEAD + h], was1_ = wastab[1 * NHEAD + h];
    float was2 = wastab[2 * NHEAD + h], was3 = wastab[3 * NHEAD + h];
    float wad0 = wadtab[0 * NHEAD + h], wad1_ = wadtab[1 * NHEAD + h];
    float wad2 = wadtab[2 * NHEAD + h], wad3 = wadtab[3 * NHEAD + h];

    float4 xd = *(const float4*)(x + (long)nid * 4);
    const float adst_h = xd.x * wad0 + xd.y * wad1_ + xd.z * wad2 + xd.w * wad3;
    const float k_h = kc[h];
    const int e0 = eoff[nid], e1 = eoff[nid + 1];

    float den = 0.f;
    float a0 = 0.f, a1 = 0.f, a2 = 0.f, a3 = 0.f;   // Σ w_e · x_e (per head)

    for (int base = e0; base < e1; base += 4) {
        int2 ep[4];
#pragma unroll
        for (int j = 0; j < 4; ++j) {
            int idx = base + j; idx = (idx < e1) ? idx : (e1 - 1);
            ep[j] = epack[idx];
        }
        float4 xs[4];
#pragma unroll
        for (int j = 0; j < 4; ++j) xs[j] = *(const float4*)(x + (long)ep[j].x * 4);
#pragma unroll
        for (int j = 0; j < 4; ++j) {
            bool valid = (base + j < e1);
            float as_e = xs[j].x * was0 + xs[j].y * was1_ + xs[j].z * was2 + xs[j].w * was3;
            float a = as_e + adst_h + __int_as_float(ep[j].y) * k_h;
            a = (a > 0.f) ? a : 0.2f * a;
            float w = valid ? __expf(a) : 0.f;
            den += w;
            a0 += xs[j].x * w; a1 += xs[j].y * w;
            a2 += xs[j].z * w; a3 += xs[j].w * w;
        }
    }

    // epilogue: expand acc4 through W1 columns (once per node)
    float inv = 1.f / (den + 1e-16f);
    float4 wk0 = *(const float4*)(w1 + 0 * HCDIM + c0);
    float4 wk1 = *(const float4*)(w1 + 1 * HCDIM + c0);
    float4 wk2 = *(const float4*)(w1 + 2 * HCDIM + c0);
    float4 wk3 = *(const float4*)(w1 + 3 * HCDIM + c0);
    float4 bv = *(const float4*)(bias + c0);
    float o0 = fmaxf((a0 * wk0.x + a1 * wk1.x + a2 * wk2.x + a3 * wk3.x) * inv + bv.x, 0.f);
    float o1 = fmaxf((a0 * wk0.y + a1 * wk1.y + a2 * wk2.y + a3 * wk3.y) * inv + bv.y, 0.f);
    float o2 = fmaxf((a0 * wk0.z + a1 * wk1.z + a2 * wk2.z + a3 * wk3.z) * inv + bv.z, 0.f);
    float o3 = fmaxf((a0 * wk0.w + a1 * wk1.w + a2 * wk2.w + a3 * wk3.w) * inv + bv.w, 0.f);
    ushort4 hv = make_ushort4(f2bf(o0), f2bf(o1), f2bf(o2), f2bf(o3));
    *(ushort4*)(outbf + (long)nid * HCDIM + c0) = hv;
}

// ---------------------------------------------------------------- gemm

// layers 2/3: [n,128] @ [128,144], plain bf16 MFMA (no split).
// W staged once per block in padded LDS (39 KB, shared by 4 waves) — the
// R12/R13 versions were W-load-latency-bound (72 KB hi/lo > 32 KB L1).
// Wave = 2 row-groups of 16 (A-reuse), block = 128 rows.
// cols 0..127 -> Ybf (bf16); col-tile 8 -> next-layer attn coeffs (fp32).
__global__ __launch_bounds__(256) void gemm_mfma(const unsigned short* __restrict__ A,
                                                 const unsigned short* __restrict__ Wt,
                                                 unsigned short* __restrict__ Ybf,
                                                 float* __restrict__ asrcn,
                                                 float* __restrict__ adstn, int n) {
    __shared__ unsigned short sW[WEXT][SWPAD];
    for (int i = threadIdx.x; i < WEXT * 16; i += 256) {
        int r = i >> 4, c = (i & 15) << 3;
        *(short8*)&sW[r][c] = *(const short8*)(Wt + r * HCDIM + c);
    }
    __syncthreads();

    const int wave = threadIdx.x >> 6;
    const int lane = threadIdx.x & 63;
    const int quad = lane >> 4;
    const int l16  = lane & 15;
    const int rowbase = (blockIdx.x * 8 + wave * 2) * 16;

    f32x4 acc[2][9];
#pragma unroll
    for (int r = 0; r < 2; ++r)
#pragma unroll
        for (int t = 0; t < 9; ++t) acc[r][t] = (f32x4){0.f, 0.f, 0.f, 0.f};

#pragma unroll
    for (int kb = 0; kb < HCDIM; kb += 32) {
        short8 a[2];
#pragma unroll
        for (int r = 0; r < 2; ++r) {
            int row = rowbase + r * 16 + l16;
            row = (row < n) ? row : (n - 1);
            a[r] = *(const short8*)(A + (long)row * HCDIM + kb + quad * 8);
        }
#pragma unroll
        for (int nt = 0; nt < 9; ++nt) {
            short8 b = *(const short8*)(&sW[nt * 16 + l16][kb + quad * 8]);
#pragma unroll
            for (int r = 0; r < 2; ++r)
                acc[r][nt] = __builtin_amdgcn_mfma_f32_16x16x32_bf16(a[r], b, acc[r][nt], 0, 0, 0);
        }
    }

    // C/D layout: col = l16, row_local = quad*4 + reg
#pragma unroll
    for (int r = 0; r < 2; ++r) {
#pragma unroll
        for (int reg = 0; reg < 4; ++reg) {
            int row = rowbase + r * 16 + quad * 4 + reg;
            if (row < n) {
                unsigned short* yp = Ybf + (long)row * HCDIM + l16;
#pragma unroll
                for (int nt = 0; nt < 8; ++nt) yp[nt * 16] = f2bf(acc[r][nt][reg]);
                float cv = acc[r][8][reg];
                if (l16 < 8) asrcn[row * NHEAD + l16] = cv;
                else         adstn[row * NHEAD + (l16 - 8)] = cv;
            }
        }
    }
}

// ---------------------------------------------------------------- aggregate (layers 2/3)

// TWO nodes per wave (32 lanes x 4 channels each); single pass, no
// max-subtraction. 4-way unrolled edge loop. h gathered as BF16 (8 B/lane);
// accumulation stays fp32.
__global__ __launch_bounds__(256) void gat_aggregate(
    const unsigned short* __restrict__ hlin, // [n,128] bf16
    const float* __restrict__ asrc,     // [n,8]
    const float* __restrict__ adst,     // [n,8]
    const int2*  __restrict__ epack,    // [E] dst-sorted {src, bits(eattr)}
    const int*   __restrict__ eoff,     // [n+1]
    const float* __restrict__ kc,       // [8] this layer
    const float* __restrict__ bias,     // [128]
    float* __restrict__ outf,           // [n,128] (split_out=0)
    unsigned short* __restrict__ outbf, // [n,128] (split_out=1) bf16
    int n, int use_loop, int split_out) {
    const int lane = threadIdx.x & 63;
    const int hl = lane & 31;
    int nid = ((blockIdx.x * 256 + threadIdx.x) >> 6) * 2 + (lane >> 5);
    if (nid >= n) return;
    const int h = hl >> 2;            // 4 lanes per head
    const int c0 = hl * 4;            // 4 contiguous channels per lane

    const float adst_h = adst[nid * NHEAD + h];
    const float k_h = kc[h];
    const int e0 = eoff[nid], e1 = eoff[nid + 1];

    float den = 0.f, sume = 0.f;
    float ax = 0.f, ay = 0.f, az = 0.f, aw = 0.f;

    for (int base = e0; base < e1; base += 4) {
        int2 ep[4];
#pragma unroll
        for (int j = 0; j < 4; ++j) {
            int idx = base + j; idx = (idx < e1) ? idx : (e1 - 1);
            ep[j] = epack[idx];
        }
        float av[4]; ushort4 hv[4];
#pragma unroll
        for (int j = 0; j < 4; ++j) {
            av[j] = asrc[ep[j].x * NHEAD + h];
            hv[j] = *(const ushort4*)(hlin + (long)ep[j].x * HCDIM + c0);
        }
#pragma unroll
        for (int j = 0; j < 4; ++j) {
            bool valid = (base + j < e1);
            float ea = __int_as_float(ep[j].y);
            float a = av[j] + adst_h + ea * k_h;
            a = (a > 0.f) ? a : 0.2f * a;
            float w = valid ? __expf(a) : 0.f;
            sume += valid ? ea : 0.f;
            den += w;
            ax += bf2f(hv[j].x) * w; ay += bf2f(hv[j].y) * w;
            az += bf2f(hv[j].z) * w; aw += bf2f(hv[j].w) * w;
        }
    }

    if (use_loop) {   // self-loop; attr = mean of incoming eattr
        float fl = sume / fmaxf((float)(e1 - e0), 1.f);
        float a = asrc[nid * NHEAD + h] + adst_h + fl * k_h;
        a = (a > 0.f) ? a : 0.2f * a;
        float w = __expf(a);
        ushort4 hv = *(const ushort4*)(hlin + (long)nid * HCDIM + c0);
        den += w;
        ax += bf2f(hv.x) * w; ay += bf2f(hv.y) * w;
        az += bf2f(hv.z) * w; aw += bf2f(hv.w) * w;
    }

    float inv = 1.f / (den + 1e-16f);
    float4 bv = *(const float4*)(bias + c0);
    float o0 = fmaxf(ax * inv + bv.x, 0.f);
    float o1 = fmaxf(ay * inv + bv.y, 0.f);
    float o2 = fmaxf(az * inv + bv.z, 0.f);
    float o3 = fmaxf(aw * inv + bv.w, 0.f);
    if (split_out) {
        ushort4 hv = make_ushort4(f2bf(o0), f2bf(o1), f2bf(o2), f2bf(o3));
        *(ushort4*)(outbf + (long)nid * HCDIM + c0) = hv;
    } else {
        *(float4*)(outf + (long)nid * HCDIM + c0) = make_float4(o0, o1, o2, o3);
    }
}

// ---------------------------------------------------------------- pool + MLP

// segmented pool: block = (graph g, chunk) over the CONTIGUOUS row range
// gstart[g]..gstart[g+1] (batch is sorted). One atomic per column per chunk.
__global__ __launch_bounds__(128) void pool_seg(const float* __restrict__ H,
                                                const int* __restrict__ gstart,
                                                float* __restrict__ gsum) {
    const int c = threadIdx.x;            // 0..127
    const int g = blockIdx.x >> 3;
    const int chunk = blockIdx.x & 7;
    int s0 = gstart[g], s1 = gstart[g + 1];
    int len = s1 - s0;
    if (len <= 0) return;
    int cl = (len + 7) >> 3;
    int i0 = s0 + chunk * cl;
    int i1 = min(i0 + cl, s1);
    if (i0 >= i1) return;
    float acc = 0.f;
    int i = i0;
    for (; i + 4 <= i1; i += 4) {
        float v0 = H[(long)i * HCDIM + c];
        float v1 = H[(long)(i + 1) * HCDIM + c];
        float v2 = H[(long)(i + 2) * HCDIM + c];
        float v3 = H[(long)(i + 3) * HCDIM + c];
        acc += (v0 + v1) + (v2 + v3);
    }
    for (; i < i1; ++i) acc += H[(long)i * HCDIM + c];
    atomicAdd(&gsum[g * HCDIM + c], acc);
}

__global__ __launch_bounds__(64) void mlp_kernel(const float* __restrict__ gsum,
                                                 const int* __restrict__ gstart,
                                                 const float* __restrict__ fw1,
                                                 const float* __restrict__ fb1,
                                                 const float* __restrict__ fw2,
                                                 const float* __restrict__ fb2,
                                                 float* __restrict__ out) {
    const int g = blockIdx.x;
    const int j = threadIdx.x;            // 0..63
    __shared__ float emb[HCDIM];
    __shared__ float gh[64];
    int cnt = gstart[g + 1] - gstart[g];
    float invc = 1.f / fmaxf((float)cnt, 1.f);
    emb[j] = gsum[g * HCDIM + j] * invc;
    emb[j + 64] = gsum[g * HCDIM + 64 + j] * invc;
    __syncthreads();
    float a = fb1[j];
    for (int k = 0; k < HCDIM; ++k) a += emb[k] * fw1[k * 64 + j];
    gh[j] = fmaxf(a, 0.f);
    __syncthreads();
    if (j < 2) {
        float o = fb2[j];
        for (int k = 0; k < 64; ++k) o += gh[k] * fw2[k * 2 + j];
        out[g * 2 + j] = o;
    }
}

// ---------------------------------------------------------------- launcher

extern "C" void kernel_launch(void* const* d_in, const int* in_sizes, int n_in,
                              void* d_out, int out_size, void* d_ws, size_t ws_size,
                              hipStream_t stream) {
    const float* x     = (const float*)d_in[0];
    const int*   eidx  = (const int*)d_in[1];
    const float* eattr = (const float*)d_in[2];
    const int*   batch = (const int*)d_in[3];
    const float* w1  = (const float*)d_in[4];
    const float* as1 = (const float*)d_in[5];
    const float* ad1 = (const float*)d_in[6];
    const float* we1 = (const float*)d_in[7];
    const float* ae1 = (const float*)d_in[8];
    const float* b1  = (const float*)d_in[9];
    const float* w2  = (const float*)d_in[10];
    const float* as2 = (const float*)d_in[11];
    const float* ad2 = (const float*)d_in[12];
    const float* we2 = (const float*)d_in[13];
    const float* ae2 = (const float*)d_in[14];
    const float* b2  = (const float*)d_in[15];
    const float* w3  = (const float*)d_in[16];
    const float* as3 = (const float*)d_in[17];
    const float* ad3 = (const float*)d_in[18];
    const float* we3 = (const float*)d_in[19];
    const float* ae3 = (const float*)d_in[20];
    const float* b3  = (const float*)d_in[21];
    const float* fw1 = (const float*)d_in[22];
    const float* fb1 = (const float*)d_in[23];
    const float* fw2 = (const float*)d_in[24];
    const float* fb2 = (const float*)d_in[25];

    const int N = in_sizes[3];
    const int E = in_sizes[2];
    const int* src = eidx;
    const int* dst = eidx + E;

    // workspace carve
    char* p = (char*)d_ws;
    auto alloc = [&](size_t bytes) {
        void* r = (void*)p;
        p += (bytes + 255) & ~(size_t)255;
        return r;
    };
    // A: gemm output in bf16 [n,128]
    unsigned short* Abf = (unsigned short*)alloc((size_t)N * HCDIM * 2);
    // B region: bf16 (layers 1-2) ALIASED with fp32 (layer 3 -> pool).
    char*  Bbuf   = (char*)alloc((size_t)N * HCDIM * 4);
    unsigned short* Bbf = (unsigned short*)Bbuf;
    float* Bf32   = (float*)Bbuf;
    float* asrcA  = (float*)alloc((size_t)N * NHEAD * 4);
    float* adstA  = (float*)alloc((size_t)N * NHEAD * 4);
    float* asrcB  = (float*)alloc((size_t)N * NHEAD * 4);
    float* adstB  = (float*)alloc((size_t)N * NHEAD * 4);
    int*   deg    = (int*)alloc((size_t)N * 4);
    int*   eoff   = (int*)alloc((size_t)(N + 1) * 4);
    int*   erank  = (int*)alloc((size_t)E * 4);
    int2*  epack  = (int2*)alloc((size_t)E * 8);
    int*   bsum   = (int*)alloc(((size_t)(N + 511) / 512) * 4);
    float* kc     = (float*)alloc(24 * 4);
    int*   gstart = (int*)alloc((NGRAPH + 1) * 4);
    float* gsum   = (float*)alloc(NGRAPH * HCDIM * 4);
    float* wastab = (float*)alloc(32 * 4);
    float* wadtab = (float*)alloc(32 * 4);
    unsigned short* wt2 = (unsigned short*)alloc(WEXT * HCDIM * 2);
    unsigned short* wt3 = (unsigned short*)alloc(WEXT * HCDIM * 2);

    const int NB = (N + 255) / 256;
    const int NB512 = (N + 511) / 512;
    const int EB = (E + 255) / 256;
    const int AGG_BLOCKS = (((N + 1) / 2) * 64 + 255) / 256;   // 2 nodes/wave
    const int GEMM_BLOCKS = (N + 127) / 128;                   // 128 rows per block

    setup0<<<NB, 256, 0, stream>>>(deg, gsum,
                                   w2, w3, wt2, wt3,
                                   we1, ae1, we2, ae2, we3, ae3, kc,
                                   as2, ad2, as3, ad3,
                                   w1, as1, ad1, wastab, wadtab,
                                   batch, gstart, N);
    count_deg<<<EB, 256, 0, stream>>>(dst, deg, erank, E);
    block_sum<<<NB512, 512, 0, stream>>>(deg, bsum, N);
    scan_final2<<<NB512, 512, 0, stream>>>(deg, bsum, NB512, eoff, N);
    scatter_edges<<<EB, 256, 0, stream>>>(src, dst, eattr, eoff, erank, epack, E);

    // layer 1 (no self loops): rank-4 accumulate + epilogue W1 expand -> bf16
    gat_aggregate1<<<AGG_BLOCKS, 256, 0, stream>>>(x, epack, eoff, w1, wastab, wadtab,
                                                   kc + 0, b1, Bbf, N);
    // layer 2: gemm (bf16, LDS-staged W) emits bf16 h2 + layer-2 coeffs
    gemm_mfma<<<GEMM_BLOCKS, 256, 0, stream>>>(Bbf, wt2, Abf, asrcB, adstB, N);
    gat_aggregate<<<AGG_BLOCKS, 256, 0, stream>>>(Abf, asrcB, adstB, epack, eoff,
                                                  kc + 8, b2, Bf32, Bbf, N, 1, 1);
    // layer 3: gemm emits bf16 h3 + layer-3 coeffs; agg out fp32 -> pool
    gemm_mfma<<<GEMM_BLOCKS, 256, 0, stream>>>(Bbf, wt3, Abf, asrcA, adstA, N);
    gat_aggregate<<<AGG_BLOCKS, 256, 0, stream>>>(Abf, asrcA, adstA, epack, eoff,
                                                  kc + 16, b3, Bf32, Bbf, N, 1, 0);

    // segmented mean-pool + MLP head
    pool_seg<<<NGRAPH * 8, 128, 0, stream>>>(Bf32, gstart, gsum);
    mlp_kernel<<<NGRAPH, 64, 0, stream>>>(gsum, gstart, fw1, fb1, fw2, fb2, (float*)d_out);
}

// Round 15
// 326.170 us; speedup vs baseline: 1.3772x; 1.0660x over previous
//
#include <hip/hip_runtime.h>
#include <hip/hip_bf16.h>
#include <math.h>

#define NHEAD 8
#define CDIM 16
#define HCDIM 128
#define NGRAPH 64
#define WEXT 144   // 128 gemm cols + 8 src-coeff cols + 8 dst-coeff cols
#define SWPAD 136  // +8 shorts pad: row stride 68 dwords == 4 mod 32 banks

typedef __attribute__((ext_vector_type(8))) short short8;
typedef __attribute__((ext_vector_type(4))) float f32x4;

static __device__ __forceinline__ unsigned short f2bf(float f) {
    unsigned u = __float_as_uint(f);
    unsigned r = (u + 0x7FFF + ((u >> 16) & 1)) >> 16;   // rne
    return (unsigned short)r;
}
static __device__ __forceinline__ float bf2f(unsigned short s) {
    return __uint_as_float(((unsigned)s) << 16);
}

// ---------------------------------------------------------------- setup

// merged: zero deg/gsum + kcoef + graph_bounds + extended weight build (bf16)
// + layer-1 coeff tables was1/wad1 [4][8]
__global__ void setup0(int* __restrict__ deg,
                       float* __restrict__ gsum,
                       const float* __restrict__ w2, const float* __restrict__ w3,
                       unsigned short* __restrict__ wt2, unsigned short* __restrict__ wt3,
                       const float* __restrict__ we1, const float* __restrict__ ae1,
                       const float* __restrict__ we2, const float* __restrict__ ae2,
                       const float* __restrict__ we3, const float* __restrict__ ae3,
                       float* __restrict__ kc,
                       const float* __restrict__ as2, const float* __restrict__ ad2,
                       const float* __restrict__ as3, const float* __restrict__ ad3,
                       const float* __restrict__ w1,
                       const float* __restrict__ as1, const float* __restrict__ ad1,
                       float* __restrict__ wastab, float* __restrict__ wadtab,
                       const int* __restrict__ batch, int* __restrict__ gstart, int n) {
    int i = blockIdx.x * 256 + threadIdx.x;
    if (i < n) deg[i] = 0;
    if (i < NGRAPH * HCDIM) gsum[i] = 0.f;
    if (i < WEXT * HCDIM) {
        int nn = i >> 7, k = i & 127;
        float v2, v3;
        if (nn < HCDIM) {
            v2 = w2[k * HCDIM + nn];
            v3 = w3[k * HCDIM + nn];
        } else if (nn < HCDIM + NHEAD) {
            int h = nn - HCDIM;
            float s2 = 0.f, s3 = 0.f;
#pragma unroll
            for (int c = 0; c < CDIM; ++c) {
                s2 += w2[k * HCDIM + h * CDIM + c] * as2[h * CDIM + c];
                s3 += w3[k * HCDIM + h * CDIM + c] * as3[h * CDIM + c];
            }
            v2 = s2; v3 = s3;
        } else {
            int h = nn - HCDIM - NHEAD;
            float s2 = 0.f, s3 = 0.f;
#pragma unroll
            for (int c = 0; c < CDIM; ++c) {
                s2 += w2[k * HCDIM + h * CDIM + c] * ad2[h * CDIM + c];
                s3 += w3[k * HCDIM + h * CDIM + c] * ad3[h * CDIM + c];
            }
            v2 = s2; v3 = s3;
        }
        wt2[nn * HCDIM + k] = f2bf(v2);
        wt3[nn * HCDIM + k] = f2bf(v3);
    }
    if (i < 24) {
        int l = i >> 3, h = i & 7;
        const float* we = (l == 0) ? we1 : ((l == 1) ? we2 : we3);
        const float* ae = (l == 0) ? ae1 : ((l == 1) ? ae2 : ae3);
        float s = 0.f;
        for (int c = 0; c < CDIM; ++c) s += we[h * CDIM + c] * ae[h * CDIM + c];
        kc[i] = s;
    }
    if (i >= 18560 && i <= 18560 + NGRAPH) {   // graph bounds, disjoint range
        int g = i - 18560;
        int lo = 0, hi = n;
        while (lo < hi) {
            int mid = (lo + hi) >> 1;
            if (batch[mid] < g) lo = mid + 1; else hi = mid;
        }
        gstart[g] = lo;
    }
    if (i >= 18700 && i < 18732) {   // layer-1 coeff tables [4][8]
        int t = i - 18700;
        int k = t >> 3, h = t & 7;
        float ss = 0.f, sd = 0.f;
#pragma unroll
        for (int c = 0; c < CDIM; ++c) {
            ss += w1[k * HCDIM + h * CDIM + c] * as1[h * CDIM + c];
            sd += w1[k * HCDIM + h * CDIM + c] * ad1[h * CDIM + c];
        }
        wastab[t] = ss;
        wadtab[t] = sd;
    }
}

// counts degree AND records each edge's within-dst rank so scatter is atomic-free.
__global__ void count_deg(const int* __restrict__ dst, int* __restrict__ deg,
                          int* __restrict__ erank, int E) {
    int e = blockIdx.x * 256 + threadIdx.x;
    if (e >= E) return;
    erank[e] = atomicAdd(&deg[dst[e]], 1);
}

__global__ __launch_bounds__(512) void block_sum(const int* __restrict__ deg,
                                                 int* __restrict__ bsum, int n) {
    __shared__ int s[512];
    int i = blockIdx.x * 512 + threadIdx.x;
    s[threadIdx.x] = (i < n) ? deg[i] : 0;
    __syncthreads();
    for (int off = 256; off > 0; off >>= 1) {
        if (threadIdx.x < off) s[threadIdx.x] += s[threadIdx.x + off];
        __syncthreads();
    }
    if (threadIdx.x == 0) bsum[blockIdx.x] = s[0];
}

// fused: every block scans the (<=512-entry) bsum array in LDS AND its own
// 512-entry deg slice, producing eoff directly.
__global__ __launch_bounds__(512) void scan_final2(const int* __restrict__ deg,
                                                   const int* __restrict__ bsum, int nb,
                                                   int* __restrict__ eoff, int n) {
    __shared__ int ls[512];
    __shared__ int s[512];
    const int t = threadIdx.x;
    ls[t] = (t < nb) ? bsum[t] : 0;
    int i = blockIdx.x * 512 + t;
    s[t] = (i < n) ? deg[i] : 0;
    __syncthreads();
    for (int off = 1; off < 512; off <<= 1) {
        int a1 = (t >= off) ? ls[t - off] : 0;
        int a2 = (t >= off) ? s[t - off] : 0;
        __syncthreads();
        ls[t] += a1; s[t] += a2;
        __syncthreads();
    }
    int base = (blockIdx.x > 0) ? ls[blockIdx.x - 1] : 0;   // exclusive block base
    if (i < n) eoff[i + 1] = base + s[t];
    if (i == 0) eoff[0] = 0;
}

// atomic-free scatter: position = eoff[dst] + precomputed rank.
__global__ void scatter_edges(const int* __restrict__ src, const int* __restrict__ dst,
                              const float* __restrict__ eattr,
                              const int* __restrict__ eoff,
                              const int* __restrict__ erank,
                              int2* __restrict__ epack, int E) {
    int e = blockIdx.x * 256 + threadIdx.x;
    if (e >= E) return;
    int p = eoff[dst[e]] + erank[e];
    epack[p] = make_int2(src[e], __float_as_int(eattr[e]));
}

// ---------------------------------------------------------------- layer-1 aggregate

// h is rank-4:  Σ_e w_e·(x_e@W1) = (Σ_e w_e·x_e)@W1.
// FOUR nodes per wave (16 lanes x 8 channels each) — α/address/exp block is
// amortized over 4 nodes. Edge loop: 5 MAC/edge; W1 expansion in epilogue.
__global__ __launch_bounds__(256) void gat_aggregate1(
    const float* __restrict__ x,        // [n,4]
    const int2*  __restrict__ epack,    // [E] dst-sorted {src, bits(eattr)}
    const int*   __restrict__ eoff,     // [n+1]
    const float* __restrict__ w1,       // [4][128]
    const float* __restrict__ wastab,   // [4][8]
    const float* __restrict__ wadtab,   // [4][8]
    const float* __restrict__ kc,       // [8]
    const float* __restrict__ bias,     // [128]
    unsigned short* __restrict__ outbf, // [n,128] bf16
    int n) {
    const int lane = threadIdx.x & 63;
    const int l16 = lane & 15;
    int nid = ((blockIdx.x * 256 + threadIdx.x) >> 6) * 4 + (lane >> 4);
    if (nid >= n) return;
    const int h = l16 >> 1;           // 2 lanes per head
    const int c0 = l16 * 8;           // 8 contiguous channels per lane

    float was0 = wastab[0 * NHEAD + h], was1_ = wastab[1 * NHEAD + h];
    float was2 = wastab[2 * NHEAD + h], was3 = wastab[3 * NHEAD + h];
    float wad0 = wadtab[0 * NHEAD + h], wad1_ = wadtab[1 * NHEAD + h];
    float wad2 = wadtab[2 * NHEAD + h], wad3 = wadtab[3 * NHEAD + h];

    float4 xd = *(const float4*)(x + (long)nid * 4);
    const float adst_h = xd.x * wad0 + xd.y * wad1_ + xd.z * wad2 + xd.w * wad3;
    const float k_h = kc[h];
    const int e0 = eoff[nid], e1 = eoff[nid + 1];

    float den = 0.f;
    float a0 = 0.f, a1 = 0.f, a2 = 0.f, a3 = 0.f;   // Σ w_e · x_e (per head)

    for (int base = e0; base < e1; base += 4) {
        int2 ep[4];
#pragma unroll
        for (int j = 0; j < 4; ++j) {
            int idx = base + j; idx = (idx < e1) ? idx : (e1 - 1);
            ep[j] = epack[idx];
        }
        float4 xs[4];
#pragma unroll
        for (int j = 0; j < 4; ++j) xs[j] = *(const float4*)(x + (long)ep[j].x * 4);
#pragma unroll
        for (int j = 0; j < 4; ++j) {
            bool valid = (base + j < e1);
            float as_e = xs[j].x * was0 + xs[j].y * was1_ + xs[j].z * was2 + xs[j].w * was3;
            float a = as_e + adst_h + __int_as_float(ep[j].y) * k_h;
            a = (a > 0.f) ? a : 0.2f * a;
            float w = valid ? __expf(a) : 0.f;
            den += w;
            a0 += xs[j].x * w; a1 += xs[j].y * w;
            a2 += xs[j].z * w; a3 += xs[j].w * w;
        }
    }

    // epilogue: expand acc4 through 8 W1 columns (once per node)
    float inv = 1.f / (den + 1e-16f);
    short8 o;
#pragma unroll
    for (int c = 0; c < 8; ++c) {
        float oc = a0 * w1[0 * HCDIM + c0 + c] + a1 * w1[1 * HCDIM + c0 + c] +
                   a2 * w1[2 * HCDIM + c0 + c] + a3 * w1[3 * HCDIM + c0 + c];
        oc = fmaxf(oc * inv + bias[c0 + c], 0.f);
        o[c] = (short)f2bf(oc);
    }
    *(short8*)(outbf + (long)nid * HCDIM + c0) = o;
}

// ---------------------------------------------------------------- gemm

// layers 2/3: [n,128] @ [128,144], plain bf16 MFMA, W staged in padded LDS.
// Wave = 2 row-groups of 16, block = 128 rows.
// cols 0..127 -> Ybf (bf16); col-tile 8 -> next-layer attn coeffs (fp32).
__global__ __launch_bounds__(256) void gemm_mfma(const unsigned short* __restrict__ A,
                                                 const unsigned short* __restrict__ Wt,
                                                 unsigned short* __restrict__ Ybf,
                                                 float* __restrict__ asrcn,
                                                 float* __restrict__ adstn, int n) {
    __shared__ unsigned short sW[WEXT][SWPAD];
    for (int i = threadIdx.x; i < WEXT * 16; i += 256) {
        int r = i >> 4, c = (i & 15) << 3;
        *(short8*)&sW[r][c] = *(const short8*)(Wt + r * HCDIM + c);
    }
    __syncthreads();

    const int wave = threadIdx.x >> 6;
    const int lane = threadIdx.x & 63;
    const int quad = lane >> 4;
    const int l16  = lane & 15;
    const int rowbase = (blockIdx.x * 8 + wave * 2) * 16;

    f32x4 acc[2][9];
#pragma unroll
    for (int r = 0; r < 2; ++r)
#pragma unroll
        for (int t = 0; t < 9; ++t) acc[r][t] = (f32x4){0.f, 0.f, 0.f, 0.f};

#pragma unroll
    for (int kb = 0; kb < HCDIM; kb += 32) {
        short8 a[2];
#pragma unroll
        for (int r = 0; r < 2; ++r) {
            int row = rowbase + r * 16 + l16;
            row = (row < n) ? row : (n - 1);
            a[r] = *(const short8*)(A + (long)row * HCDIM + kb + quad * 8);
        }
#pragma unroll
        for (int nt = 0; nt < 9; ++nt) {
            short8 b = *(const short8*)(&sW[nt * 16 + l16][kb + quad * 8]);
#pragma unroll
            for (int r = 0; r < 2; ++r)
                acc[r][nt] = __builtin_amdgcn_mfma_f32_16x16x32_bf16(a[r], b, acc[r][nt], 0, 0, 0);
        }
    }

    // C/D layout: col = l16, row_local = quad*4 + reg
#pragma unroll
    for (int r = 0; r < 2; ++r) {
#pragma unroll
        for (int reg = 0; reg < 4; ++reg) {
            int row = rowbase + r * 16 + quad * 4 + reg;
            if (row < n) {
                unsigned short* yp = Ybf + (long)row * HCDIM + l16;
#pragma unroll
                for (int nt = 0; nt < 8; ++nt) yp[nt * 16] = f2bf(acc[r][nt][reg]);
                float cv = acc[r][8][reg];
                if (l16 < 8) asrcn[row * NHEAD + l16] = cv;
                else         adstn[row * NHEAD + (l16 - 8)] = cv;
            }
        }
    }
}

// ---------------------------------------------------------------- aggregate (layers 2/3)

// FOUR nodes per wave (16 lanes x 8 bf16 channels each); single pass, no
// max-subtraction. 4-way unrolled edge loop. h gathered as BF16 (16 B/lane);
// accumulation fp32; output bf16.
__global__ __launch_bounds__(256) void gat_aggregate(
    const unsigned short* __restrict__ hlin, // [n,128] bf16
    const float* __restrict__ asrc,     // [n,8]
    const float* __restrict__ adst,     // [n,8]
    const int2*  __restrict__ epack,    // [E] dst-sorted {src, bits(eattr)}
    const int*   __restrict__ eoff,     // [n+1]
    const float* __restrict__ kc,       // [8] this layer
    const float* __restrict__ bias,     // [128]
    unsigned short* __restrict__ out,   // [n,128] bf16
    int n, int use_loop) {
    const int lane = threadIdx.x & 63;
    const int l16 = lane & 15;
    int nid = ((blockIdx.x * 256 + threadIdx.x) >> 6) * 4 + (lane >> 4);
    if (nid >= n) return;
    const int h = l16 >> 1;           // 2 lanes per head
    const int c0 = l16 * 8;           // 8 contiguous channels per lane

    const float adst_h = adst[nid * NHEAD + h];
    const float k_h = kc[h];
    const int e0 = eoff[nid], e1 = eoff[nid + 1];

    float den = 0.f, sume = 0.f;
    float acc[8];
#pragma unroll
    for (int c = 0; c < 8; ++c) acc[c] = 0.f;

    for (int base = e0; base < e1; base += 4) {
        int2 ep[4];
#pragma unroll
        for (int j = 0; j < 4; ++j) {
            int idx = base + j; idx = (idx < e1) ? idx : (e1 - 1);
            ep[j] = epack[idx];
        }
        float av[4]; short8 hv[4];
#pragma unroll
        for (int j = 0; j < 4; ++j) {
            av[j] = asrc[ep[j].x * NHEAD + h];
            hv[j] = *(const short8*)(hlin + (long)ep[j].x * HCDIM + c0);
        }
#pragma unroll
        for (int j = 0; j < 4; ++j) {
            bool valid = (base + j < e1);
            float ea = __int_as_float(ep[j].y);
            float a = av[j] + adst_h + ea * k_h;
            a = (a > 0.f) ? a : 0.2f * a;
            float w = valid ? __expf(a) : 0.f;
            sume += valid ? ea : 0.f;
            den += w;
#pragma unroll
            for (int c = 0; c < 8; ++c)
                acc[c] += bf2f((unsigned short)hv[j][c]) * w;
        }
    }

    if (use_loop) {   // self-loop; attr = mean of incoming eattr
        float fl = sume / fmaxf((float)(e1 - e0), 1.f);
        float a = asrc[nid * NHEAD + h] + adst_h + fl * k_h;
        a = (a > 0.f) ? a : 0.2f * a;
        float w = __expf(a);
        short8 hv = *(const short8*)(hlin + (long)nid * HCDIM + c0);
        den += w;
#pragma unroll
        for (int c = 0; c < 8; ++c)
            acc[c] += bf2f((unsigned short)hv[c]) * w;
    }

    float inv = 1.f / (den + 1e-16f);
    short8 o;
#pragma unroll
    for (int c = 0; c < 8; ++c) {
        float oc = fmaxf(acc[c] * inv + bias[c0 + c], 0.f);
        o[c] = (short)f2bf(oc);
    }
    *(short8*)(out + (long)nid * HCDIM + c0) = o;
}

// ---------------------------------------------------------------- pool + MLP

// segmented pool over bf16 h3: block = (graph g, chunk) over the CONTIGUOUS
// row range gstart[g]..gstart[g+1]. One atomic per column per chunk.
__global__ __launch_bounds__(128) void pool_seg(const unsigned short* __restrict__ H,
                                                const int* __restrict__ gstart,
                                                float* __restrict__ gsum) {
    const int c = threadIdx.x;            // 0..127
    const int g = blockIdx.x >> 3;
    const int chunk = blockIdx.x & 7;
    int s0 = gstart[g], s1 = gstart[g + 1];
    int len = s1 - s0;
    if (len <= 0) return;
    int cl = (len + 7) >> 3;
    int i0 = s0 + chunk * cl;
    int i1 = min(i0 + cl, s1);
    if (i0 >= i1) return;
    float acc = 0.f;
    int i = i0;
    for (; i + 4 <= i1; i += 4) {
        float v0 = bf2f(H[(long)i * HCDIM + c]);
        float v1 = bf2f(H[(long)(i + 1) * HCDIM + c]);
        float v2 = bf2f(H[(long)(i + 2) * HCDIM + c]);
        float v3 = bf2f(H[(long)(i + 3) * HCDIM + c]);
        acc += (v0 + v1) + (v2 + v3);
    }
    for (; i < i1; ++i) acc += bf2f(H[(long)i * HCDIM + c]);
    atomicAdd(&gsum[g * HCDIM + c], acc);
}

__global__ __launch_bounds__(64) void mlp_kernel(const float* __restrict__ gsum,
                                                 const int* __restrict__ gstart,
                                                 const float* __restrict__ fw1,
                                                 const float* __restrict__ fb1,
                                                 const float* __restrict__ fw2,
                                                 const float* __restrict__ fb2,
                                                 float* __restrict__ out) {
    const int g = blockIdx.x;
    const int j = threadIdx.x;            // 0..63
    __shared__ float emb[HCDIM];
    __shared__ float gh[64];
    int cnt = gstart[g + 1] - gstart[g];
    float invc = 1.f / fmaxf((float)cnt, 1.f);
    emb[j] = gsum[g * HCDIM + j] * invc;
    emb[j + 64] = gsum[g * HCDIM + 64 + j] * invc;
    __syncthreads();
    float a = fb1[j];
    for (int k = 0; k < HCDIM; ++k) a += emb[k] * fw1[k * 64 + j];
    gh[j] = fmaxf(a, 0.f);
    __syncthreads();
    if (j < 2) {
        float o = fb2[j];
        for (int k = 0; k < 64; ++k) o += gh[k] * fw2[k * 2 + j];
        out[g * 2 + j] = o;
    }
}

// ---------------------------------------------------------------- launcher

extern "C" void kernel_launch(void* const* d_in, const int* in_sizes, int n_in,
                              void* d_out, int out_size, void* d_ws, size_t ws_size,
                              hipStream_t stream) {
    const float* x     = (const float*)d_in[0];
    const int*   eidx  = (const int*)d_in[1];
    const float* eattr = (const float*)d_in[2];
    const int*   batch = (const int*)d_in[3];
    const float* w1  = (const float*)d_in[4];
    const float* as1 = (const float*)d_in[5];
    const float* ad1 = (const float*)d_in[6];
    const float* we1 = (const float*)d_in[7];
    const float* ae1 = (const float*)d_in[8];
    const float* b1  = (const float*)d_in[9];
    const float* w2  = (const float*)d_in[10];
    const float* as2 = (const float*)d_in[11];
    const float* ad2 = (const float*)d_in[12];
    const float* we2 = (const float*)d_in[13];
    const float* ae2 = (const float*)d_in[14];
    const float* b2  = (const float*)d_in[15];
    const float* w3  = (const float*)d_in[16];
    const float* as3 = (const float*)d_in[17];
    const float* ad3 = (const float*)d_in[18];
    const float* we3 = (const float*)d_in[19];
    const float* ae3 = (const float*)d_in[20];
    const float* b3  = (const float*)d_in[21];
    const float* fw1 = (const float*)d_in[22];
    const float* fb1 = (const float*)d_in[23];
    const float* fw2 = (const float*)d_in[24];
    const float* fb2 = (const float*)d_in[25];

    const int N = in_sizes[3];
    const int E = in_sizes[2];
    const int* src = eidx;
    const int* dst = eidx + E;

    // workspace carve
    char* p = (char*)d_ws;
    auto alloc = [&](size_t bytes) {
        void* r = (void*)p;
        p += (bytes + 255) & ~(size_t)255;
        return r;
    };
    unsigned short* Abf = (unsigned short*)alloc((size_t)N * HCDIM * 2);  // gemm out
    unsigned short* Bbf = (unsigned short*)alloc((size_t)N * HCDIM * 2);  // agg out
    float* asrcA  = (float*)alloc((size_t)N * NHEAD * 4);
    float* adstA  = (float*)alloc((size_t)N * NHEAD * 4);
    float* asrcB  = (float*)alloc((size_t)N * NHEAD * 4);
    float* adstB  = (float*)alloc((size_t)N * NHEAD * 4);
    int*   deg    = (int*)alloc((size_t)N * 4);
    int*   eoff   = (int*)alloc((size_t)(N + 1) * 4);
    int*   erank  = (int*)alloc((size_t)E * 4);
    int2*  epack  = (int2*)alloc((size_t)E * 8);
    int*   bsum   = (int*)alloc(((size_t)(N + 511) / 512) * 4);
    float* kc     = (float*)alloc(24 * 4);
    int*   gstart = (int*)alloc((NGRAPH + 1) * 4);
    float* gsum   = (float*)alloc(NGRAPH * HCDIM * 4);
    float* wastab = (float*)alloc(32 * 4);
    float* wadtab = (float*)alloc(32 * 4);
    unsigned short* wt2 = (unsigned short*)alloc(WEXT * HCDIM * 2);
    unsigned short* wt3 = (unsigned short*)alloc(WEXT * HCDIM * 2);

    const int NB = (N + 255) / 256;
    const int NB512 = (N + 511) / 512;
    const int EB = (E + 255) / 256;
    const int AGG_BLOCKS = (((N + 3) / 4) * 64 + 255) / 256;   // 4 nodes/wave
    const int GEMM_BLOCKS = (N + 127) / 128;                   // 128 rows per block

    setup0<<<NB, 256, 0, stream>>>(deg, gsum,
                                   w2, w3, wt2, wt3,
                                   we1, ae1, we2, ae2, we3, ae3, kc,
                                   as2, ad2, as3, ad3,
                                   w1, as1, ad1, wastab, wadtab,
                                   batch, gstart, N);
    count_deg<<<EB, 256, 0, stream>>>(dst, deg, erank, E);
    block_sum<<<NB512, 512, 0, stream>>>(deg, bsum, N);
    scan_final2<<<NB512, 512, 0, stream>>>(deg, bsum, NB512, eoff, N);
    scatter_edges<<<EB, 256, 0, stream>>>(src, dst, eattr, eoff, erank, epack, E);

    // layer 1 (no self loops): rank-4 accumulate + epilogue W1 expand -> bf16
    gat_aggregate1<<<AGG_BLOCKS, 256, 0, stream>>>(x, epack, eoff, w1, wastab, wadtab,
                                                   kc + 0, b1, Bbf, N);
    // layer 2: gemm (bf16, LDS-staged W) emits bf16 h2 + layer-2 coeffs
    gemm_mfma<<<GEMM_BLOCKS, 256, 0, stream>>>(Bbf, wt2, Abf, asrcB, adstB, N);
    gat_aggregate<<<AGG_BLOCKS, 256, 0, stream>>>(Abf, asrcB, adstB, epack, eoff,
                                                  kc + 8, b2, Bbf, N, 1);
    // layer 3: gemm emits bf16 h3 + layer-3 coeffs; agg out bf16 -> pool
    gemm_mfma<<<GEMM_BLOCKS, 256, 0, stream>>>(Bbf, wt3, Abf, asrcA, adstA, N);
    gat_aggregate<<<AGG_BLOCKS, 256, 0, stream>>>(Abf, asrcA, adstA, epack, eoff,
                                                  kc + 16, b3, Bbf, N, 1);

    // segmented mean-pool (bf16 in) + MLP head
    pool_seg<<<NGRAPH * 8, 128, 0, stream>>>(Bbf, gstart, gsum);
    mlp_kernel<<<NGRAPH, 64, 0, stream>>>(gsum, gstart, fw1, fb1, fw2, fb2, (float*)d_out);
}